// Round 14
// baseline (351.309 us; speedup 1.0000x reference)
//
#include <hip/hip_runtime.h>
#include <hip/hip_fp16.h>
#include <math.h>

#define SLOPE 0.2f
#define LOG2E 1.4426950408889634f

// DPP add over lane groups: quad_perm xor1/xor2, row_half_mirror.
#define DPP_ADD(x, ctrl) \
    ((x) + __int_as_float(__builtin_amdgcn_update_dpp( \
        0, __float_as_int(x), (ctrl), 0xF, 0xF, true)))

// ============ CSR build: counting-sort binning (6 dispatches) ============
// Proven multi-kernel chain (round-3 lesson: no contended global atomics;
// round-9 lesson: no grid.sync -- ~130us per sync on this chip).
// EPB=2048 (round-18: 489 blocks fills the chip; 8192 left half idle).
//   kH1: per-block LDS histogram of dst>>8 -> hist[bucket][block]
//   k_scan1: chunk-exclusive scan of hist + chunk totals -> blk
//   k_scan3: adds sum(blk[0..b)) -> hs = global run offsets
//   kH2: re-read edges, claim rank via LDS atomic, write pairs[run+rank]
//   kB3: per-bucket PAD-16 totals (LDS hist) -> btot
//   kB4: bucket base = sum(btot[0..b)); LDS hist + 256-wide prefix ->
//        rp/deg + col placement + zero-fill of pad slots (no col memset).
// xl/xr are fp16 -> col holds src*128 (fp16 row byte offset).

#define NPB 256               // nodes per bucket (dst >> 8)
#define EPB 2048              // edges per sort block (489 blocks at E=1M)
#define MAXBK 2048            // LDS histogram capacity (N up to 512k)

__global__ __launch_bounds__(256) void kH1(const int* __restrict__ ei,
                                           int* __restrict__ hist,
                                           int E, int nbk, int nblkE) {
    __shared__ int h[MAXBK];
    int t = threadIdx.x, b = blockIdx.x;
    for (int i = t; i < nbk; i += 256) h[i] = 0;
    __syncthreads();
    int e0 = b * EPB, e1 = min(e0 + EPB, E);
    for (int e = e0 + t; e < e1; e += 256)
        atomicAdd(&h[ei[E + e] >> 8], 1);
    __syncthreads();
    for (int i = t; i < nbk; i += 256)
        hist[i * nblkE + b] = h[i];   // hist ~765KB: stays in L2
}

__global__ __launch_bounds__(256) void k_scan1(const int* __restrict__ deg,
                                               int* __restrict__ rp,
                                               int* __restrict__ blk, int n) {
    __shared__ int sd[256];
    int t = threadIdx.x;
    int base = blockIdx.x * 1024 + t * 4;
    int v0 = 0, v1 = 0, v2 = 0, v3 = 0;
    if (base + 0 < n) v0 = deg[base + 0];
    if (base + 1 < n) v1 = deg[base + 1];
    if (base + 2 < n) v2 = deg[base + 2];
    if (base + 3 < n) v3 = deg[base + 3];
    int s = v0 + v1 + v2 + v3;
    sd[t] = s;
    __syncthreads();
    for (int off = 1; off < 256; off <<= 1) {
        int x = (t >= off) ? sd[t - off] : 0;
        __syncthreads();
        sd[t] += x;
        __syncthreads();
    }
    int ex = sd[t] - s;
    if (t == 255) blk[blockIdx.x] = sd[255];
    if (base + 0 < n) rp[base + 0] = ex; ex += v0;
    if (base + 1 < n) rp[base + 1] = ex; ex += v1;
    if (base + 2 < n) rp[base + 2] = ex; ex += v2;
    if (base + 3 < n) rp[base + 3] = ex;
}

// k_scan3: block b sums blk[0..b) itself (nblk <= a few hundred).
__global__ __launch_bounds__(256) void k_scan3(int* __restrict__ rp,
                                               const int* __restrict__ blk,
                                               int n) {
    __shared__ int red[256];
    int t = threadIdx.x, b = blockIdx.x;
    int v = 0;
    for (int i = t; i < b; i += 256) v += blk[i];
    red[t] = v;
    __syncthreads();
    for (int off = 128; off; off >>= 1) {
        if (t < off) red[t] += red[t + off];
        __syncthreads();
    }
    int off0 = red[0];
    int base = b * 1024 + t * 4;
    #pragma unroll
    for (int i = 0; i < 4; i++) {
        int idx = base + i;
        if (idx < n) rp[idx] += off0;
    }
}

__global__ __launch_bounds__(256) void kH2(const int* __restrict__ ei,
                                           const int* __restrict__ hs,
                                           int* __restrict__ pairs,
                                           int E, int nbk, int nblkE) {
    __shared__ int soff[MAXBK];       // this block's run starts; LDS-claimed
    int t = threadIdx.x, b = blockIdx.x;
    for (int i = t; i < nbk; i += 256) soff[i] = hs[i * nblkE + b];
    __syncthreads();
    int e0 = b * EPB, e1 = min(e0 + EPB, E);
    for (int e = e0 + t; e < e1; e += 256) {
        int s = ei[e], d = ei[E + e];
        int slot = atomicAdd(&soff[d >> 8], 1);   // LDS atomic: no contention
        pairs[slot] = (s << 8) | (d & (NPB - 1));
    }
}

// kB3: per-bucket PAD-16 edge total.
__global__ __launch_bounds__(256) void kB3(const int* __restrict__ hs,
                                           const int* __restrict__ pairs,
                                           int* __restrict__ btot,
                                           int E, int nbk, int nblkE) {
    __shared__ int sdeg[NPB];
    __shared__ int red[256];
    int t = threadIdx.x, b = blockIdx.x;
    sdeg[t] = 0;
    __syncthreads();
    int s0 = hs[b * nblkE];
    int s1 = (b + 1 < nbk) ? hs[(b + 1) * nblkE] : E;
    for (int i = s0 + t; i < s1; i += 256)
        atomicAdd(&sdeg[pairs[i] & (NPB - 1)], 1);
    __syncthreads();
    red[t] = (sdeg[t] + 15) & ~15;
    __syncthreads();
    for (int off = 128; off; off >>= 1) {
        if (t < off) red[t] += red[t + off];
        __syncthreads();
    }
    if (t == 0) btot[b] = red[0];
}

// kB4: bucket base computed in-kernel (sum of btot[0..b)); rebuild LDS hist,
// 256-wide pad-16 prefix -> rp/deg; place col with LDS cursors and zero-fill
// pad slots. col stores src*128 (byte offset into the fp16 xl array).
__global__ __launch_bounds__(256) void kB4(const int* __restrict__ hs,
                                           const int* __restrict__ pairs,
                                           const int* __restrict__ btot,
                                           int* __restrict__ rp,
                                           int* __restrict__ deg,
                                           int* __restrict__ col,
                                           int E, int nbk, int nblkE, int n) {
    __shared__ int sdeg[NPB];
    __shared__ int spfx[NPB];
    int t = threadIdx.x, b = blockIdx.x;

    // bucket base: sum btot[0..b)
    int v = 0;
    for (int i = t; i < b; i += 256) v += btot[i];
    spfx[t] = v;
    __syncthreads();
    for (int off = 128; off; off >>= 1) {
        if (t < off) spfx[t] += spfx[t + off];
        __syncthreads();
    }
    int bb = spfx[0];
    __syncthreads();

    sdeg[t] = 0;
    __syncthreads();
    int s0 = hs[b * nblkE];
    int s1 = (b + 1 < nbk) ? hs[(b + 1) * nblkE] : E;
    for (int i = s0 + t; i < s1; i += 256)
        atomicAdd(&sdeg[pairs[i] & (NPB - 1)], 1);
    __syncthreads();
    int cnt = sdeg[t];
    int pv = (cnt + 15) & ~15;
    spfx[t] = pv;
    __syncthreads();
    for (int off = 1; off < 256; off <<= 1) {
        int x = (t >= off) ? spfx[t - off] : 0;
        __syncthreads();
        spfx[t] += x;
        __syncthreads();
    }
    int rpt = bb + spfx[t] - pv;
    int node = b * NPB + t;
    if (node < n) { rp[node] = rpt; deg[node] = cnt; }
    __syncthreads();
    sdeg[t] = rpt;                 // reuse as placement cursor
    __syncthreads();
    for (int i = s0 + t; i < s1; i += 256) {
        int p = pairs[i];
        int slot = atomicAdd(&sdeg[p & (NPB - 1)], 1);
        col[slot] = (p & ~(NPB - 1)) >> 1;   // src*128: fp16 row byte offset
    }
    // zero the pad slots (masked gathers hit row 0, weights masked to 0)
    if (node < n)
        for (int i = rpt + cnt; i < rpt + pv; i++) col[i] = 0;
}

// ---------------- GEMM (layer 0): xl = x @ Wl, xr = x @ Wr (fp16 out) -------
// Round-12/13 shape (proven): 512 threads, 128 rows, thread = 4r x 8c.
// LDS = 32 KB sW + 34 KB sx -> 2 blocks x 8 waves = 16 waves/CU.

__global__ __launch_bounds__(512) void k_gemm(const float* __restrict__ in,
                                              const float* __restrict__ Wl,
                                              const float* __restrict__ Wr,
                                              __half* __restrict__ xl,
                                              __half* __restrict__ xr, int n) {
    __shared__ float4 sW[64 * 32];    // [k][jq]: jq<16 -> Wl cols, else Wr
    __shared__ float  sx[128 * 68];   // 128 rows, pad-68 floats (272 B) stride

    int t = threadIdx.x;
    int base = blockIdx.x * 128;

    float4 xs[4];
    int xrow[4], xkq[4];
    #pragma unroll
    for (int s = 0; s < 4; s++) {
        int i = t + 512 * s;           // 2048 float4 = 128 rows x 16 quads
        int row = i >> 4, kq = i & 15;
        int g = base + row;
        if (g > n - 1) g = n - 1;      // clamp: always-valid load, no UB
        xs[s] = *(const float4*)(in + (size_t)g * 64 + kq * 4);
        xrow[s] = row; xkq[s] = kq;
    }
    for (int i = t; i < 2048; i += 512) {
        int k = i >> 5, jg = i & 31;
        const float* src = (jg < 16) ? (Wl + k * 64 + jg * 4)
                                     : (Wr + k * 64 + (jg - 16) * 4);
        sW[i] = *(const float4*)src;
    }
    #pragma unroll
    for (int s = 0; s < 4; s++)
        *(float4*)(sx + xrow[s] * 68 + xkq[s] * 4) = xs[s];
    __syncthreads();

    int rt = t & 31;   // rows rt, rt+32, rt+64, rt+96
    int ct = t >> 5;   // 16 col tiles of 8 cols (2 quads)
    const float* sxp = sx + rt * 68;

    float4 acc[4][2];
    #pragma unroll
    for (int r = 0; r < 4; r++)
        #pragma unroll
        for (int j = 0; j < 2; j++) acc[r][j] = make_float4(0.f, 0.f, 0.f, 0.f);

    #pragma unroll 1
    for (int k0 = 0; k0 < 64; k0 += 4) {
        float4 xv[4];
        #pragma unroll
        for (int r = 0; r < 4; r++)
            xv[r] = *(const float4*)(sxp + r * (32 * 68) + k0);
        #pragma unroll
        for (int kk = 0; kk < 4; kk++) {
            float4 w0 = sW[(k0 + kk) * 32 + ct * 2 + 0];
            float4 w1 = sW[(k0 + kk) * 32 + ct * 2 + 1];
            #pragma unroll
            for (int r = 0; r < 4; r++) {
                float xk = (kk == 0) ? xv[r].x : (kk == 1) ? xv[r].y
                         : (kk == 2) ? xv[r].z : xv[r].w;
                acc[r][0].x += xk * w0.x;
                acc[r][0].y += xk * w0.y;
                acc[r][0].z += xk * w0.z;
                acc[r][0].w += xk * w0.w;
                acc[r][1].x += xk * w1.x;
                acc[r][1].y += xk * w1.y;
                acc[r][1].z += xk * w1.z;
                acc[r][1].w += xk * w1.w;
            }
        }
    }

    __half* outh = (ct < 8) ? xl : xr;
    int cq = (ct & 7) * 8;
    #pragma unroll
    for (int r = 0; r < 4; r++) {
        int g = base + rt + 32 * r;
        if (g < n) {
            union { int4 i4; __half2 h[4]; } u;
            u.h[0] = __floats2half2_rn(acc[r][0].x, acc[r][0].y);
            u.h[1] = __floats2half2_rn(acc[r][0].z, acc[r][0].w);
            u.h[2] = __floats2half2_rn(acc[r][1].x, acc[r][1].y);
            u.h[3] = __floats2half2_rn(acc[r][1].z, acc[r][1].w);
            *(int4*)(outh + (size_t)g * 64 + cq) = u.i4;   // 16B store
        }
    }
}

// -------- FUSED: node-aggregate(layer l) -> LDS h-tile -> gemm(layer l+1) ----
// Round-19: the h round-trip (k_node writes 25MB fp32, next k_gemm re-reads
// 25.6MB) never leaves the chip. Block = 128 nodes: node phase (8 waves x
// 16 nodes, proven round-12 wave body, relu'd fp32 result straight into the
// gemm sx tile), one __syncthreads, then the proven round-12 gemm shape out
// of LDS. W staged before the node phase so its latency hides under
// aggregation. h stays fp32 -> zero precision change. Caller double-buffers
// xl/xr (fused reads all of xl_in while writing xl_out -> must not alias).

__global__ __launch_bounds__(512) void k_fused(const __half* __restrict__ xli,
                                               const __half* __restrict__ xri,
                                               const int* __restrict__ rp,
                                               const int* __restrict__ deg,
                                               const int* __restrict__ col,
                                               const float* __restrict__ A,
                                               const float* __restrict__ Bv,
                                               const float* __restrict__ Wl,
                                               const float* __restrict__ Wr,
                                               __half* __restrict__ xlo,
                                               __half* __restrict__ xro,
                                               int n) {
    __shared__ float4 sW[64 * 32];    // next layer's W
    __shared__ float  sx[128 * 68];   // h tile (node-phase output, fp32)

    int t = threadIdx.x;
    int base = blockIdx.x * 128;

    // stage W first: independent of node phase, loads complete under it
    for (int i = t; i < 2048; i += 512) {
        int k = i >> 5, jg = i & 31;
        const float* src = (jg < 16) ? (Wl + k * 64 + jg * 4)
                                     : (Wr + k * 64 + (jg - 16) * 4);
        sW[i] = *(const float4*)src;
    }

    // ---- node phase: wave wv aggregates nodes base+wv*16 .. +15 ----
    int lane = t & 63;
    int wv = t >> 6;                  // 0..7
    int grp = lane >> 5;              // 0: even edges, 1: odd edges
    int s = lane & 31;
    int chn = ((s >> 3) << 4) + ((s & 7) << 1);   // h*16 + o2*2
    unsigned cofs = (unsigned)chn * 2u;           // byte offset in fp16 row
    float2 a2 = *(const float2*)(A + chn);
    a2.x *= LOG2E; a2.y *= LOG2E;
    float2 b2 = *(const float2*)(Bv + chn);
    const char* xlb = (const char*)xli;

    #pragma unroll 1
    for (int ni = 0; ni < 16; ni++) {
        int local = wv * 16 + ni;
        int node = __builtin_amdgcn_readfirstlane(base + local);
        if (node >= n) break;         // wave-uniform

        float2 xr2 = __half22float2(
            *(const __half2*)(xri + (size_t)node * 64 + chn));
        int start = rp[node];
        int d = deg[node];
        int nb = (d + 7) >> 3;        // batches of 8 edges = 4 pairs
        const int* cp = col + start;

        float den = 0.f, ax = 0.f, ay = 0.f;

        auto batch = [&](const float2 (&v)[4], int ebase, bool full) {
            #pragma unroll
            for (int j = 0; j < 4; j++) {
                float sx_ = v[j].x + xr2.x;
                float sy_ = v[j].y + xr2.y;
                sx_ = fmaxf(sx_, SLOPE * sx_);    // leaky_relu (slope < 1)
                sy_ = fmaxf(sy_, SLOPE * sy_);
                float q = sx_ * a2.x + sy_ * a2.y;
                q = DPP_ADD(q, 0xB1);             // xor1
                q = DPP_ADD(q, 0x4E);             // xor2 -> quad sums
                q = DPP_ADD(q, 0x141);            // half_mirror -> 8-lane sum
                if (!full) {
                    int eidx = ebase + 2 * j + grp;
                    if (eidx >= d) q = -INFINITY;
                }
                float w = __builtin_amdgcn_exp2f(q);   // exp2(-inf)=0 mask
                den += w;
                ax += w * v[j].x;
                ay += w * v[j].y;
            }
        };
        auto gather = [&](float2 (&v)[4], const int* q) {
            int c[8];
            *(int4*)(c + 0) = *(const int4*)(q + 0);
            *(int4*)(c + 4) = *(const int4*)(q + 4);
            #pragma unroll
            for (int j = 0; j < 4; j++) {
                unsigned cc = (unsigned)(grp ? c[2 * j + 1] : c[2 * j]);
                v[j] = __half22float2(*(const __half2*)(xlb + (cc + cofs)));
            }
        };

        float2 v[4];
        if (nb > 0) gather(v, cp);
        #pragma unroll 1
        for (int b = 0; b < nb - 1; b++) {
            float2 vN[4];
            gather(vN, cp + (b + 1) * 8);
            batch(v, b * 8, true);
            #pragma unroll
            for (int j = 0; j < 4; j++) v[j] = vN[j];
        }
        if (nb > 0) batch(v, (nb - 1) * 8, false);

        den += __shfl_xor(den, 32, 64);
        ax  += __shfl_xor(ax, 32, 64);
        ay  += __shfl_xor(ay, 32, 64);

        float inv = 1.f / (den + 1e-16f);
        float ox = fmaxf(ax * inv + b2.x, 0.f);   // fused layers always relu
        float oy = fmaxf(ay * inv + b2.y, 0.f);
        if (grp == 0)
            *(float2*)(sx + local * 68 + chn) = make_float2(ox, oy);
    }
    __syncthreads();

    // ---- gemm phase: identical round-12 shape, reads sx (h tile) ----
    int rt = t & 31;   // rows rt, rt+32, rt+64, rt+96
    int ct = t >> 5;   // 16 col tiles of 8 cols (2 quads)
    const float* sxp = sx + rt * 68;

    float4 acc[4][2];
    #pragma unroll
    for (int r = 0; r < 4; r++)
        #pragma unroll
        for (int j = 0; j < 2; j++) acc[r][j] = make_float4(0.f, 0.f, 0.f, 0.f);

    #pragma unroll 1
    for (int k0 = 0; k0 < 64; k0 += 4) {
        float4 xv[4];
        #pragma unroll
        for (int r = 0; r < 4; r++)
            xv[r] = *(const float4*)(sxp + r * (32 * 68) + k0);
        #pragma unroll
        for (int kk = 0; kk < 4; kk++) {
            float4 w0 = sW[(k0 + kk) * 32 + ct * 2 + 0];
            float4 w1 = sW[(k0 + kk) * 32 + ct * 2 + 1];
            #pragma unroll
            for (int r = 0; r < 4; r++) {
                float xk = (kk == 0) ? xv[r].x : (kk == 1) ? xv[r].y
                         : (kk == 2) ? xv[r].z : xv[r].w;
                acc[r][0].x += xk * w0.x;
                acc[r][0].y += xk * w0.y;
                acc[r][0].z += xk * w0.z;
                acc[r][0].w += xk * w0.w;
                acc[r][1].x += xk * w1.x;
                acc[r][1].y += xk * w1.y;
                acc[r][1].z += xk * w1.z;
                acc[r][1].w += xk * w1.w;
            }
        }
    }

    __half* outh = (ct < 8) ? xlo : xro;
    int cq = (ct & 7) * 8;
    #pragma unroll
    for (int r = 0; r < 4; r++) {
        int g = base + rt + 32 * r;
        if (g < n) {
            union { int4 i4; __half2 h[4]; } u;
            u.h[0] = __floats2half2_rn(acc[r][0].x, acc[r][0].y);
            u.h[1] = __floats2half2_rn(acc[r][0].z, acc[r][0].w);
            u.h[2] = __floats2half2_rn(acc[r][1].x, acc[r][1].y);
            u.h[3] = __floats2half2_rn(acc[r][1].z, acc[r][1].w);
            *(int4*)(outh + (size_t)g * 64 + cq) = u.i4;   // 16B store
        }
    }
}

// ---------------- node kernel (final layer): writes d_out fp32 ----------------
// Round-12 shape (proven): fp16 half2 gathers, fp32 math, no relu.

__global__ __launch_bounds__(256) void k_node(const __half* __restrict__ xl,
                                              const __half* __restrict__ xr,
                                              const int* __restrict__ rp,
                                              const int* __restrict__ deg,
                                              const int* __restrict__ col,
                                              const float* __restrict__ A,
                                              const float* __restrict__ Bv,
                                              float* __restrict__ outp,
                                              int n, int relu) {
    int lane = threadIdx.x & 63;
    int node = __builtin_amdgcn_readfirstlane(blockIdx.x * 4 + (threadIdx.x >> 6));
    if (node >= n) return;             // scalar branch
    int grp = lane >> 5;               // 0: even edges, 1: odd edges
    int s   = lane & 31;
    int chn = ((s >> 3) << 4) + ((s & 7) << 1);   // h*16 + o2*2
    unsigned cofs = (unsigned)chn * 2u;           // byte offset in fp16 row

    float2 xr2 = __half22float2(*(const __half2*)(xr + (size_t)node * 64 + chn));
    float2 a2  = *(const float2*)(A + chn);
    a2.x *= LOG2E; a2.y *= LOG2E;      // exp2-domain logits
    float2 b2  = *(const float2*)(Bv + chn);

    int start = rp[node];              // uniform -> s_load
    int d = deg[node];
    int nb = (d + 7) >> 3;             // batches of 8 edges = 4 pairs
    const int* cp = col + start;
    const char* xlb = (const char*)xl;

    float den = 0.f;
    float ax = 0.f, ay = 0.f;

    auto batch = [&](const float2 (&v)[4], int ebase, bool full) {
        #pragma unroll
        for (int j = 0; j < 4; j++) {
            float sx_ = v[j].x + xr2.x;
            float sy_ = v[j].y + xr2.y;
            sx_ = fmaxf(sx_, SLOPE * sx_);        // leaky_relu (slope < 1)
            sy_ = fmaxf(sy_, SLOPE * sy_);
            float q = sx_ * a2.x + sy_ * a2.y;    // per-lane partial dot
            q = DPP_ADD(q, 0xB1);                 // xor1
            q = DPP_ADD(q, 0x4E);                 // xor2 -> quad sums
            q = DPP_ADD(q, 0x141);                // half_mirror -> 8-lane sum
            if (!full) {
                int eidx = ebase + 2 * j + grp;   // per-lane; tail only
                if (eidx >= d) q = -INFINITY;
            }
            float w = __builtin_amdgcn_exp2f(q);  // masked: exp2(-inf)=0
            den += w;
            ax += w * v[j].x;
            ay += w * v[j].y;
        }
    };

    auto gather = [&](float2 (&v)[4], const int* q) {
        int c[8];
        *(int4*)(c + 0) = *(const int4*)(q + 0);  // uniform -> s_load
        *(int4*)(c + 4) = *(const int4*)(q + 4);
        #pragma unroll
        for (int j = 0; j < 4; j++) {
            unsigned cc = (unsigned)(grp ? c[2 * j + 1] : c[2 * j]);
            v[j] = __half22float2(*(const __half2*)(xlb + (cc + cofs)));
        }
    };

    float2 v[4];
    if (nb > 0) gather(v, cp);

    #pragma unroll 1
    for (int b = 0; b < nb - 1; b++) {
        float2 vN[4];
        gather(vN, cp + (b + 1) * 8);
        batch(v, b * 8, true);                    // full: no masking
        #pragma unroll
        for (int j = 0; j < 4; j++) v[j] = vN[j];
    }
    if (nb > 0) batch(v, (nb - 1) * 8, false);    // tail: mask eidx >= d

    // combine the two halves (even-edge and odd-edge partials)
    den += __shfl_xor(den, 32, 64);
    ax  += __shfl_xor(ax, 32, 64);
    ay  += __shfl_xor(ay, 32, 64);

    float inv = 1.f / (den + 1e-16f);
    float ox = ax * inv + b2.x;
    float oy = ay * inv + b2.y;
    if (relu) { ox = fmaxf(ox, 0.f); oy = fmaxf(oy, 0.f); }
    if (grp == 0)
        *(float2*)(outp + (size_t)node * 64 + chn) = make_float2(ox, oy);
}

// ---------------- launcher ----------------

extern "C" void kernel_launch(void* const* d_in, const int* in_sizes, int n_in,
                              void* d_out, int out_size, void* d_ws, size_t ws_size,
                              hipStream_t stream) {
    const float* x = (const float*)d_in[0];
    const int* ei = (const int*)d_in[1];
    int N = in_sizes[0] / 64;
    int E = in_sizes[1] / 2;

    const float* Wl[3] = {(const float*)d_in[2], (const float*)d_in[6], (const float*)d_in[10]};
    const float* Wr[3] = {(const float*)d_in[3], (const float*)d_in[7], (const float*)d_in[11]};
    const float* Av[3] = {(const float*)d_in[4], (const float*)d_in[8], (const float*)d_in[12]};
    const float* Bv[3] = {(const float*)d_in[5], (const float*)d_in[9], (const float*)d_in[13]};

    char* w = (char*)d_ws;
    auto carve = [&](size_t bytes) {
        void* p = (void*)w;
        w += (bytes + 255) & ~(size_t)255;
        return p;
    };
    int NBK    = (N + NPB - 1) / NPB;               // buckets of 256 nodes
    int NBLK_E = (E + EPB - 1) / EPB;               // sort blocks of 2048 edges
    size_t histN = (size_t)NBK * NBLK_E;
    size_t colN = (size_t)E + 15 * (size_t)N + 64;  // pad-16 segments + slack
    __half* xlA  = (__half*)carve((size_t)N * 64 * 2);
    __half* xrA  = (__half*)carve((size_t)N * 64 * 2);
    __half* xlB  = (__half*)carve((size_t)N * 64 * 2);
    __half* xrB  = (__half*)carve((size_t)N * 64 * 2);
    int*   rp    = (int*)carve((size_t)N * 4);
    int*   deg   = (int*)carve((size_t)N * 4);
    int*   col   = (int*)carve(colN * 4);
    int*   pairs = (int*)carve((size_t)E * 4);
    int*   hist  = (int*)carve(histN * 4);
    int*   hs    = (int*)carve(histN * 4);
    int*   btot  = (int*)carve((size_t)NBK * 4);
    int*   blkB  = (int*)carve(512 * 4);

    int nblkH1024 = (int)((histN + 1023) / 1024);
    int gemm_grid  = (N + 127) / 128;
    int fused_grid = (N + 127) / 128;
    int node_grid  = (N + 3) / 4;

    // counting sort by dst bucket (no contended global atomics anywhere)
    kH1<<<NBLK_E, 256, 0, stream>>>(ei, hist, E, NBK, NBLK_E);
    k_scan1<<<nblkH1024, 256, 0, stream>>>(hist, hs, blkB, (int)histN);
    k_scan3<<<nblkH1024, 256, 0, stream>>>(hs, blkB, (int)histN);
    kH2<<<NBLK_E, 256, 0, stream>>>(ei, hs, pairs, E, NBK, NBLK_E);

    // per-bucket: padded totals -> rp/deg/col (+pad zero-fill, in-kernel base)
    kB3<<<NBK, 256, 0, stream>>>(hs, pairs, btot, E, NBK, NBLK_E);
    kB4<<<NBK, 256, 0, stream>>>(hs, pairs, btot, rp, deg, col, E, NBK, NBLK_E, N);

    // layer 0 gemm: x -> A buffers
    k_gemm<<<gemm_grid, 512, 0, stream>>>(x, Wl[0], Wr[0], xlA, xrA, N);
    // fused node(l=0)+gemm(l=1): A -> B   (h tile never leaves LDS)
    k_fused<<<fused_grid, 512, 0, stream>>>(xlA, xrA, rp, deg, col,
                                            Av[0], Bv[0], Wl[1], Wr[1],
                                            xlB, xrB, N);
    // fused node(l=1)+gemm(l=2): B -> A
    k_fused<<<fused_grid, 512, 0, stream>>>(xlB, xrB, rp, deg, col,
                                            Av[1], Bv[1], Wl[2], Wr[2],
                                            xlA, xrA, N);
    // final node (l=2): A -> d_out (fp32, no relu)
    k_node<<<node_grid, 256, 0, stream>>>(xlA, xrA, rp, deg, col, Av[2], Bv[2],
                                          (float*)d_out, N, 0);
}

// Round 15
// 322.364 us; speedup vs baseline: 1.0898x; 1.0898x over previous
//
#include <hip/hip_runtime.h>
#include <hip/hip_fp16.h>
#include <math.h>

#define SLOPE 0.2f
#define LOG2E 1.4426950408889634f

// DPP add over lane groups: quad_perm xor1/xor2, row_half_mirror.
#define DPP_ADD(x, ctrl) \
    ((x) + __int_as_float(__builtin_amdgcn_update_dpp( \
        0, __float_as_int(x), (ctrl), 0xF, 0xF, true)))

// ============ CSR build: counting-sort binning (6 dispatches) ============
// Proven multi-kernel chain (round-3 lesson: no contended global atomics;
// round-9 lesson: no grid.sync -- ~130us per sync on this chip; round-14
// lesson: never fuse the latency-bound gather phase into an occupancy-
// capped compute kernel -- it kills the TLP that hides gather latency).
// EPB=2048 (round-18: 489 blocks fills the chip; 8192 left half idle).
//   kH1: per-block LDS histogram of dst>>8 -> hist[bucket][block]
//   k_scan1: chunk-exclusive scan of hist + chunk totals -> blk
//   k_scan3: adds sum(blk[0..b)) -> hs = global run offsets
//   kH2: re-read edges, claim rank via LDS atomic, write pairs[run+rank]
//   kB3: per-bucket PAD-16 totals (LDS hist) -> btot
//   kB4: bucket base = sum(btot[0..b)); LDS hist + 256-wide prefix ->
//        rp/deg + col placement + zero-fill of pad slots (no col memset).
// xl/xr are fp16 -> col holds src*128 (fp16 row byte offset).

#define NPB 256               // nodes per bucket (dst >> 8)
#define EPB 2048              // edges per sort block (489 blocks at E=1M)
#define MAXBK 2048            // LDS histogram capacity (N up to 512k)

__global__ __launch_bounds__(256) void kH1(const int* __restrict__ ei,
                                           int* __restrict__ hist,
                                           int E, int nbk, int nblkE) {
    __shared__ int h[MAXBK];
    int t = threadIdx.x, b = blockIdx.x;
    for (int i = t; i < nbk; i += 256) h[i] = 0;
    __syncthreads();
    int e0 = b * EPB, e1 = min(e0 + EPB, E);
    for (int e = e0 + t; e < e1; e += 256)
        atomicAdd(&h[ei[E + e] >> 8], 1);
    __syncthreads();
    for (int i = t; i < nbk; i += 256)
        hist[i * nblkE + b] = h[i];   // hist ~765KB: stays in L2
}

__global__ __launch_bounds__(256) void k_scan1(const int* __restrict__ deg,
                                               int* __restrict__ rp,
                                               int* __restrict__ blk, int n) {
    __shared__ int sd[256];
    int t = threadIdx.x;
    int base = blockIdx.x * 1024 + t * 4;
    int v0 = 0, v1 = 0, v2 = 0, v3 = 0;
    if (base + 0 < n) v0 = deg[base + 0];
    if (base + 1 < n) v1 = deg[base + 1];
    if (base + 2 < n) v2 = deg[base + 2];
    if (base + 3 < n) v3 = deg[base + 3];
    int s = v0 + v1 + v2 + v3;
    sd[t] = s;
    __syncthreads();
    for (int off = 1; off < 256; off <<= 1) {
        int x = (t >= off) ? sd[t - off] : 0;
        __syncthreads();
        sd[t] += x;
        __syncthreads();
    }
    int ex = sd[t] - s;
    if (t == 255) blk[blockIdx.x] = sd[255];
    if (base + 0 < n) rp[base + 0] = ex; ex += v0;
    if (base + 1 < n) rp[base + 1] = ex; ex += v1;
    if (base + 2 < n) rp[base + 2] = ex; ex += v2;
    if (base + 3 < n) rp[base + 3] = ex;
}

// k_scan3: block b sums blk[0..b) itself (nblk <= a few hundred).
__global__ __launch_bounds__(256) void k_scan3(int* __restrict__ rp,
                                               const int* __restrict__ blk,
                                               int n) {
    __shared__ int red[256];
    int t = threadIdx.x, b = blockIdx.x;
    int v = 0;
    for (int i = t; i < b; i += 256) v += blk[i];
    red[t] = v;
    __syncthreads();
    for (int off = 128; off; off >>= 1) {
        if (t < off) red[t] += red[t + off];
        __syncthreads();
    }
    int off0 = red[0];
    int base = b * 1024 + t * 4;
    #pragma unroll
    for (int i = 0; i < 4; i++) {
        int idx = base + i;
        if (idx < n) rp[idx] += off0;
    }
}

__global__ __launch_bounds__(256) void kH2(const int* __restrict__ ei,
                                           const int* __restrict__ hs,
                                           int* __restrict__ pairs,
                                           int E, int nbk, int nblkE) {
    __shared__ int soff[MAXBK];       // this block's run starts; LDS-claimed
    int t = threadIdx.x, b = blockIdx.x;
    for (int i = t; i < nbk; i += 256) soff[i] = hs[i * nblkE + b];
    __syncthreads();
    int e0 = b * EPB, e1 = min(e0 + EPB, E);
    for (int e = e0 + t; e < e1; e += 256) {
        int s = ei[e], d = ei[E + e];
        int slot = atomicAdd(&soff[d >> 8], 1);   // LDS atomic: no contention
        pairs[slot] = (s << 8) | (d & (NPB - 1));
    }
}

// kB3: per-bucket PAD-16 edge total.
__global__ __launch_bounds__(256) void kB3(const int* __restrict__ hs,
                                           const int* __restrict__ pairs,
                                           int* __restrict__ btot,
                                           int E, int nbk, int nblkE) {
    __shared__ int sdeg[NPB];
    __shared__ int red[256];
    int t = threadIdx.x, b = blockIdx.x;
    sdeg[t] = 0;
    __syncthreads();
    int s0 = hs[b * nblkE];
    int s1 = (b + 1 < nbk) ? hs[(b + 1) * nblkE] : E;
    for (int i = s0 + t; i < s1; i += 256)
        atomicAdd(&sdeg[pairs[i] & (NPB - 1)], 1);
    __syncthreads();
    red[t] = (sdeg[t] + 15) & ~15;
    __syncthreads();
    for (int off = 128; off; off >>= 1) {
        if (t < off) red[t] += red[t + off];
        __syncthreads();
    }
    if (t == 0) btot[b] = red[0];
}

// kB4: bucket base computed in-kernel (sum of btot[0..b)); rebuild LDS hist,
// 256-wide pad-16 prefix -> rp/deg; place col with LDS cursors and zero-fill
// pad slots. col stores src*128 (byte offset into the fp16 xl array).
__global__ __launch_bounds__(256) void kB4(const int* __restrict__ hs,
                                           const int* __restrict__ pairs,
                                           const int* __restrict__ btot,
                                           int* __restrict__ rp,
                                           int* __restrict__ deg,
                                           int* __restrict__ col,
                                           int E, int nbk, int nblkE, int n) {
    __shared__ int sdeg[NPB];
    __shared__ int spfx[NPB];
    int t = threadIdx.x, b = blockIdx.x;

    // bucket base: sum btot[0..b)
    int v = 0;
    for (int i = t; i < b; i += 256) v += btot[i];
    spfx[t] = v;
    __syncthreads();
    for (int off = 128; off; off >>= 1) {
        if (t < off) spfx[t] += spfx[t + off];
        __syncthreads();
    }
    int bb = spfx[0];
    __syncthreads();

    sdeg[t] = 0;
    __syncthreads();
    int s0 = hs[b * nblkE];
    int s1 = (b + 1 < nbk) ? hs[(b + 1) * nblkE] : E;
    for (int i = s0 + t; i < s1; i += 256)
        atomicAdd(&sdeg[pairs[i] & (NPB - 1)], 1);
    __syncthreads();
    int cnt = sdeg[t];
    int pv = (cnt + 15) & ~15;
    spfx[t] = pv;
    __syncthreads();
    for (int off = 1; off < 256; off <<= 1) {
        int x = (t >= off) ? spfx[t - off] : 0;
        __syncthreads();
        spfx[t] += x;
        __syncthreads();
    }
    int rpt = bb + spfx[t] - pv;
    int node = b * NPB + t;
    if (node < n) { rp[node] = rpt; deg[node] = cnt; }
    __syncthreads();
    sdeg[t] = rpt;                 // reuse as placement cursor
    __syncthreads();
    for (int i = s0 + t; i < s1; i += 256) {
        int p = pairs[i];
        int slot = atomicAdd(&sdeg[p & (NPB - 1)], 1);
        col[slot] = (p & ~(NPB - 1)) >> 1;   // src*128: fp16 row byte offset
    }
    // zero the pad slots (masked gathers hit row 0, weights masked to 0)
    if (node < n)
        for (int i = rpt + cnt; i < rpt + pv; i++) col[i] = 0;
}

// ---------------- GEMM: xl = in @ Wl, xr = in @ Wr (fp16 out) ----------------
// Round-12/13 shape (measured best): 512 threads, 128 rows, thread = 4r x 8c
// (the proven round-2 thread tile). LDS = 32 KB sW + 34 KB sx -> 2 blocks x
// 8 waves = 16 waves/CU. fp32 accumulate, fp16 packed store.

__global__ __launch_bounds__(512) void k_gemm(const float* __restrict__ in,
                                              const float* __restrict__ Wl,
                                              const float* __restrict__ Wr,
                                              __half* __restrict__ xl,
                                              __half* __restrict__ xr, int n) {
    __shared__ float4 sW[64 * 32];    // [k][jq]: jq<16 -> Wl cols, else Wr
    __shared__ float  sx[128 * 68];   // 128 rows, pad-68 floats (272 B) stride

    int t = threadIdx.x;
    int base = blockIdx.x * 128;

    float4 xs[4];
    int xrow[4], xkq[4];
    #pragma unroll
    for (int s = 0; s < 4; s++) {
        int i = t + 512 * s;           // 2048 float4 = 128 rows x 16 quads
        int row = i >> 4, kq = i & 15;
        int g = base + row;
        if (g > n - 1) g = n - 1;      // clamp: always-valid load, no UB
        xs[s] = *(const float4*)(in + (size_t)g * 64 + kq * 4);
        xrow[s] = row; xkq[s] = kq;
    }
    for (int i = t; i < 2048; i += 512) {
        int k = i >> 5, jg = i & 31;
        const float* src = (jg < 16) ? (Wl + k * 64 + jg * 4)
                                     : (Wr + k * 64 + (jg - 16) * 4);
        sW[i] = *(const float4*)src;
    }
    #pragma unroll
    for (int s = 0; s < 4; s++)
        *(float4*)(sx + xrow[s] * 68 + xkq[s] * 4) = xs[s];
    __syncthreads();

    int rt = t & 31;   // rows rt, rt+32, rt+64, rt+96
    int ct = t >> 5;   // 16 col tiles of 8 cols (2 quads)
    const float* sxp = sx + rt * 68;

    float4 acc[4][2];
    #pragma unroll
    for (int r = 0; r < 4; r++)
        #pragma unroll
        for (int j = 0; j < 2; j++) acc[r][j] = make_float4(0.f, 0.f, 0.f, 0.f);

    #pragma unroll 1
    for (int k0 = 0; k0 < 64; k0 += 4) {
        float4 xv[4];
        #pragma unroll
        for (int r = 0; r < 4; r++)
            xv[r] = *(const float4*)(sxp + r * (32 * 68) + k0);
        #pragma unroll
        for (int kk = 0; kk < 4; kk++) {
            float4 w0 = sW[(k0 + kk) * 32 + ct * 2 + 0];
            float4 w1 = sW[(k0 + kk) * 32 + ct * 2 + 1];
            #pragma unroll
            for (int r = 0; r < 4; r++) {
                float xk = (kk == 0) ? xv[r].x : (kk == 1) ? xv[r].y
                         : (kk == 2) ? xv[r].z : xv[r].w;
                acc[r][0].x += xk * w0.x;
                acc[r][0].y += xk * w0.y;
                acc[r][0].z += xk * w0.z;
                acc[r][0].w += xk * w0.w;
                acc[r][1].x += xk * w1.x;
                acc[r][1].y += xk * w1.y;
                acc[r][1].z += xk * w1.z;
                acc[r][1].w += xk * w1.w;
            }
        }
    }

    __half* outh = (ct < 8) ? xl : xr;
    int cq = (ct & 7) * 8;
    #pragma unroll
    for (int r = 0; r < 4; r++) {
        int g = base + rt + 32 * r;
        if (g < n) {
            union { int4 i4; __half2 h[4]; } u;
            u.h[0] = __floats2half2_rn(acc[r][0].x, acc[r][0].y);
            u.h[1] = __floats2half2_rn(acc[r][0].z, acc[r][0].w);
            u.h[2] = __floats2half2_rn(acc[r][1].x, acc[r][1].y);
            u.h[3] = __floats2half2_rn(acc[r][1].z, acc[r][1].w);
            *(int4*)(outh + (size_t)g * 64 + cq) = u.i4;   // 16B store
        }
    }
}

// ---------------- node kernel: no-max softmax GATv2 aggregation ----------------
// Round-12 shape (measured best): fp16 half2 gathers (128B rows), fp32 math.
// Each lane holds 2 channels: head = 8 lanes, node = 32 lanes, two wave
// halves process two edges of the same node. Batches of 8 edges; 1-deep
// prefetch; tail masked q=-inf. Pad-16 zero-filled segments. One node per
// wave, 25k blocks -> ~100k independent waves (the TLP that hides gather
// latency -- round-14 showed fusing this away costs +56us).

__global__ __launch_bounds__(256) void k_node(const __half* __restrict__ xl,
                                              const __half* __restrict__ xr,
                                              const int* __restrict__ rp,
                                              const int* __restrict__ deg,
                                              const int* __restrict__ col,
                                              const float* __restrict__ A,
                                              const float* __restrict__ Bv,
                                              float* __restrict__ outp,
                                              int n, int relu) {
    int lane = threadIdx.x & 63;
    int node = __builtin_amdgcn_readfirstlane(blockIdx.x * 4 + (threadIdx.x >> 6));
    if (node >= n) return;             // scalar branch
    int grp = lane >> 5;               // 0: even edges, 1: odd edges
    int s   = lane & 31;
    int chn = ((s >> 3) << 4) + ((s & 7) << 1);   // h*16 + o2*2
    unsigned cofs = (unsigned)chn * 2u;           // byte offset in fp16 row

    float2 xr2 = __half22float2(*(const __half2*)(xr + (size_t)node * 64 + chn));
    float2 a2  = *(const float2*)(A + chn);
    a2.x *= LOG2E; a2.y *= LOG2E;      // exp2-domain logits
    float2 b2  = *(const float2*)(Bv + chn);

    int start = rp[node];              // uniform -> s_load
    int d = deg[node];
    int nb = (d + 7) >> 3;             // batches of 8 edges = 4 pairs
    const int* cp = col + start;
    const char* xlb = (const char*)xl;

    float den = 0.f;
    float ax = 0.f, ay = 0.f;

    auto batch = [&](const float2 (&v)[4], int ebase, bool full) {
        #pragma unroll
        for (int j = 0; j < 4; j++) {
            float sx_ = v[j].x + xr2.x;
            float sy_ = v[j].y + xr2.y;
            sx_ = fmaxf(sx_, SLOPE * sx_);        // leaky_relu (slope < 1)
            sy_ = fmaxf(sy_, SLOPE * sy_);
            float q = sx_ * a2.x + sy_ * a2.y;    // per-lane partial dot
            q = DPP_ADD(q, 0xB1);                 // xor1
            q = DPP_ADD(q, 0x4E);                 // xor2 -> quad sums
            q = DPP_ADD(q, 0x141);                // half_mirror -> 8-lane sum
            if (!full) {
                int eidx = ebase + 2 * j + grp;   // per-lane; tail only
                if (eidx >= d) q = -INFINITY;
            }
            float w = __builtin_amdgcn_exp2f(q);  // masked: exp2(-inf)=0
            den += w;
            ax += w * v[j].x;
            ay += w * v[j].y;
        }
    };

    auto gather = [&](float2 (&v)[4], const int* q) {
        int c[8];
        *(int4*)(c + 0) = *(const int4*)(q + 0);  // uniform -> s_load
        *(int4*)(c + 4) = *(const int4*)(q + 4);
        #pragma unroll
        for (int j = 0; j < 4; j++) {
            unsigned cc = (unsigned)(grp ? c[2 * j + 1] : c[2 * j]);
            v[j] = __half22float2(*(const __half2*)(xlb + (cc + cofs)));
        }
    };

    float2 v[4];
    if (nb > 0) gather(v, cp);

    #pragma unroll 1
    for (int b = 0; b < nb - 1; b++) {
        float2 vN[4];
        gather(vN, cp + (b + 1) * 8);
        batch(v, b * 8, true);                    // full: no masking
        #pragma unroll
        for (int j = 0; j < 4; j++) v[j] = vN[j];
    }
    if (nb > 0) batch(v, (nb - 1) * 8, false);    // tail: mask eidx >= d

    // combine the two halves (even-edge and odd-edge partials)
    den += __shfl_xor(den, 32, 64);
    ax  += __shfl_xor(ax, 32, 64);
    ay  += __shfl_xor(ay, 32, 64);

    float inv = 1.f / (den + 1e-16f);
    float ox = ax * inv + b2.x;
    float oy = ay * inv + b2.y;
    if (relu) { ox = fmaxf(ox, 0.f); oy = fmaxf(oy, 0.f); }
    if (grp == 0)
        *(float2*)(outp + (size_t)node * 64 + chn) = make_float2(ox, oy);
}

// ---------------- launcher ----------------

extern "C" void kernel_launch(void* const* d_in, const int* in_sizes, int n_in,
                              void* d_out, int out_size, void* d_ws, size_t ws_size,
                              hipStream_t stream) {
    const float* x = (const float*)d_in[0];
    const int* ei = (const int*)d_in[1];
    int N = in_sizes[0] / 64;
    int E = in_sizes[1] / 2;

    const float* Wl[3] = {(const float*)d_in[2], (const float*)d_in[6], (const float*)d_in[10]};
    const float* Wr[3] = {(const float*)d_in[3], (const float*)d_in[7], (const float*)d_in[11]};
    const float* Av[3] = {(const float*)d_in[4], (const float*)d_in[8], (const float*)d_in[12]};
    const float* Bv[3] = {(const float*)d_in[5], (const float*)d_in[9], (const float*)d_in[13]};

    char* w = (char*)d_ws;
    auto carve = [&](size_t bytes) {
        void* p = (void*)w;
        w += (bytes + 255) & ~(size_t)255;
        return p;
    };
    int NBK    = (N + NPB - 1) / NPB;               // buckets of 256 nodes
    int NBLK_E = (E + EPB - 1) / EPB;               // sort blocks of 2048 edges
    size_t histN = (size_t)NBK * NBLK_E;
    size_t colN = (size_t)E + 15 * (size_t)N + 64;  // pad-16 segments + slack
    __half* xl   = (__half*)carve((size_t)N * 64 * 2);
    __half* xr   = (__half*)carve((size_t)N * 64 * 2);
    float* h     = (float*)carve((size_t)N * 64 * 4);
    int*   rp    = (int*)carve((size_t)N * 4);
    int*   deg   = (int*)carve((size_t)N * 4);
    int*   col   = (int*)carve(colN * 4);
    int*   pairs = (int*)carve((size_t)E * 4);
    int*   hist  = (int*)carve(histN * 4);
    int*   hs    = (int*)carve(histN * 4);
    int*   btot  = (int*)carve((size_t)NBK * 4);
    int*   blkB  = (int*)carve(512 * 4);

    int nblkH1024 = (int)((histN + 1023) / 1024);
    int gemm_grid = (N + 127) / 128;
    int node_grid = (N + 3) / 4;

    // counting sort by dst bucket (no contended global atomics anywhere)
    kH1<<<NBLK_E, 256, 0, stream>>>(ei, hist, E, NBK, NBLK_E);
    k_scan1<<<nblkH1024, 256, 0, stream>>>(hist, hs, blkB, (int)histN);
    k_scan3<<<nblkH1024, 256, 0, stream>>>(hs, blkB, (int)histN);
    kH2<<<NBLK_E, 256, 0, stream>>>(ei, hs, pairs, E, NBK, NBLK_E);

    // per-bucket: padded totals -> rp/deg/col (+pad zero-fill, in-kernel base)
    kB3<<<NBK, 256, 0, stream>>>(hs, pairs, btot, E, NBK, NBLK_E);
    kB4<<<NBK, 256, 0, stream>>>(hs, pairs, btot, rp, deg, col, E, NBK, NBLK_E, N);

    const float* in_l = x;
    for (int l = 0; l < 3; l++) {
        float* out_l = (l == 2) ? (float*)d_out : h;
        int relu = (l < 2) ? 1 : 0;
        k_gemm<<<gemm_grid, 512, 0, stream>>>(in_l, Wl[l], Wr[l], xl, xr, N);
        k_node<<<node_grid, 256, 0, stream>>>(xl, xr, rp, deg, col, Av[l], Bv[l],
                                              out_l, N, relu);
        in_l = h;
    }
}